// Round 16
// baseline (315.798 us; speedup 1.0000x reference)
//
#include <hip/hip_runtime.h>

#define HH 128
#define WW 256
#define NCP 32           // 64 channels -> 32 channel-pairs
#define PLANE 32768      // H*W dwords per plane
#define PACKED_DWORDS 4194304ull   // packed S: 4 b * 32 cp * 32768
#define ZOFF PACKED_DWORDS         // zero region: 1024 dwords after packed S

typedef unsigned int u32;
typedef _Float16 f16;
typedef f16 f16x2 __attribute__((ext_vector_type(2)));
typedef u32 u32x2 __attribute__((ext_vector_type(2)));
typedef u32 u32x4 __attribute__((ext_vector_type(4)));

union U32H2 { u32 u; f16x2 h; };

__device__ __forceinline__ void gload_lds16(const u32* g, u32* l) {
  __builtin_amdgcn_global_load_lds(
      (const __attribute__((address_space(1))) u32*)g,
      (__attribute__((address_space(3))) u32*)l, 16, 0, 0);
}

// ---- pack S + zero the OOB region (block 0) ----
__global__ __launch_bounds__(256) void pack_s(
    const float* __restrict__ src, u32* __restrict__ dst, u32* __restrict__ zws)
{
  if (blockIdx.x == 0)                      // 256 thr x 16B = 4 KB zero region
    ((float4*)zws)[threadIdx.x] = make_float4(0.f, 0.f, 0.f, 0.f);
  const int di  = blockIdx.x * 1024 + threadIdx.x * 4;
  const int p   = di & (PLANE - 1);
  const int cpb = di >> 15;
  const int bI  = cpb >> 5, cp = cpb & 31;
  const size_t s0 = ((size_t)(bI * 64 + cp * 2)) * PLANE + p;
  const float4 x = *(const float4*)(src + s0);
  const float4 y = *(const float4*)(src + s0 + PLANE);
  U32H2 h0, h1, h2, h3;
  h0.h = f16x2{(f16)x.x, (f16)y.x};
  h1.h = f16x2{(f16)x.y, (f16)y.y};
  h2.h = f16x2{(f16)x.z, (f16)y.z};
  h3.h = f16x2{(f16)x.w, (f16)y.w};
  *(u32x4*)(dst + di) = (u32x4){h0.u, h1.u, h2.u, h3.u};
}

// ---- correlation: block=(b,h,w-half), 5 dy-pair waves, WPT=2 per lane.
// Per cp per wave: 2 S-row gloads (33-lane, full 136-dw padded half-row each)
// + 2 fp32 F dwordx2 loads. No barriers; counted vmcnt; zero pads only at the
// true array edge (DMA never touches them).
__global__ __launch_bounds__(320, 5) void corr_f16(
    const u32* __restrict__ ps, const float* __restrict__ first,
    const u32* __restrict__ zws, float* __restrict__ out)
{
  __shared__ u32 lds[5][4 * 2 * 136];       // 5 waves x 4 slots x 2 rows; 21760 B

  const int tid   = threadIdx.x;
  const int lane  = tid & 63;
  const int wv    = __builtin_amdgcn_readfirstlane(tid >> 6);  // 0..4
  const int bid   = blockIdx.x;
  const int xcd   = bid & 7;                // contiguous 16-row h band per XCD
  const int rest  = bid >> 3;               // 0..127
  const int idx   = rest & 63;
  const int whalf = rest >> 6;              // same (b,h) pair -> same XCD
  const int h     = xcd * 16 + (idx & 15);
  const int b     = idx >> 4;
  const int w0    = whalf * 128;
  const int l2    = lane * 2;
  const int dy0   = 2 * wv;

  u32* Sl = &lds[wv][0];                    // rows of [4 pad | 128 | 4 pad]=136 dw
  // doff: LDS dest offset for the 132-dw staged span; pad at the array edge only.
  const int doff    = (w0 == 0) ? 4 : 0;    // left: data 4..135; right: 0..131
  const int padbase = (w0 == 0) ? 0 : 132;
  if (lane < 32) {                          // zero 4 edge dws x 8 ring rows
    const int row = lane >> 2, pd = lane & 3;
    Sl[row * 136 + padbase + pd] = 0;
  }

  const int gh0 = h + dy0 - 4, gh1 = gh0 + 1;
  const bool ok0 = (0 <= gh0 && gh0 < HH), ok1 = (0 <= gh1 && gh1 < HH);
  const u32* sbase = ps + (size_t)(b * NCP) * PLANE;
  const int soff = w0 - 4 + doff;           // 0 (left) or 124 (right)
  const int l4 = lane * 4;                  // gload src: lane*16B
  const u32* sg0 = (ok0 ? sbase + (size_t)gh0 * WW : zws) + soff + l4;
  const u32* sg1 = (ok1 ? sbase + (size_t)gh1 * WW : zws) + soff + l4;
  const size_t st0 = ok0 ? PLANE : 0, st1 = ok1 ? PLANE : 0;
  const float* fg = first + (size_t)(b * 64) * PLANE + (size_t)h * WW + w0 + l2;
  float* ob = out + (size_t)(b * 81 + dy0 * 9) * PLANE + (size_t)h * WW + w0 + l2;

  float2 frx[4], fry[4];                    // F ring, literal indices only
  float acc[36];                            // [2 dy][9 dx][2 cols]
#pragma unroll
  for (int k = 0; k < 36; ++k) acc[k] = 0.f;

#define PAIRI(sl) do {                                            \
    if (lane < 33) {  /* 33 lanes x 16B = 132 dw staged span */   \
      gload_lds16(sg0, Sl + ((sl) * 2 + 0) * 136 + doff);         \
      gload_lds16(sg1, Sl + ((sl) * 2 + 1) * 136 + doff);         \
    }                                                             \
    sg0 += st0; sg1 += st1;                                       \
    frx[sl] = *(const float2*)fg;                                 \
    fry[sl] = *(const float2*)(fg + PLANE);                       \
    fg += 2 * (size_t)PLANE;                                      \
  } while (0)

  PAIRI(0); PAIRI(1); PAIRI(2);             // 3 pairs = 12 vmem in flight

  // j = LITERAL ring slot; window rel dws 2l..2l+9 via 5 aligned b64 reads.
#define ITER(j, WN, DOP) do {                                     \
    if      ((WN) == 8) asm volatile("s_waitcnt vmcnt(8)" ::: "memory"); \
    else if ((WN) == 4) asm volatile("s_waitcnt vmcnt(4)" ::: "memory"); \
    else                asm volatile("s_waitcnt vmcnt(0)" ::: "memory"); \
    __builtin_amdgcn_sched_barrier(0);                            \
    U32H2 f_[2];                                                  \
    f_[0].h = f16x2{(f16)frx[j].x, (f16)fry[j].x};                \
    f_[1].h = f16x2{(f16)frx[j].y, (f16)fry[j].y};                \
    const u32* R0 = Sl + ((j) * 2 + 0) * 136 + l2;                \
    const u32* R1 = Sl + ((j) * 2 + 1) * 136 + l2;                \
    const u32x2 a0 = *(const u32x2*)(R0);                         \
    const u32x2 a1 = *(const u32x2*)(R0 + 2);                     \
    const u32x2 a2 = *(const u32x2*)(R0 + 4);                     \
    const u32x2 a3 = *(const u32x2*)(R0 + 6);                     \
    const u32x2 a4 = *(const u32x2*)(R0 + 8);                     \
    const u32x2 b0 = *(const u32x2*)(R1);                         \
    const u32x2 b1 = *(const u32x2*)(R1 + 2);                     \
    const u32x2 b2 = *(const u32x2*)(R1 + 4);                     \
    const u32x2 b3 = *(const u32x2*)(R1 + 6);                     \
    const u32x2 b4 = *(const u32x2*)(R1 + 8);                     \
    if (DOP) PAIRI(((j) + 3) & 3);                                \
    U32H2 s_[10];                                                 \
    s_[0].u = a0[0]; s_[1].u = a0[1]; s_[2].u = a1[0]; s_[3].u = a1[1]; \
    s_[4].u = a2[0]; s_[5].u = a2[1]; s_[6].u = a3[0]; s_[7].u = a3[1]; \
    s_[8].u = a4[0]; s_[9].u = a4[1];                             \
    _Pragma("unroll") for (int dx = 0; dx < 9; ++dx)              \
      _Pragma("unroll") for (int i = 0; i < 2; ++i)               \
        acc[dx * 2 + i] = __builtin_amdgcn_fdot2(                 \
            f_[i].h, s_[i + dx].h, acc[dx * 2 + i], false);       \
    s_[0].u = b0[0]; s_[1].u = b0[1]; s_[2].u = b1[0]; s_[3].u = b1[1]; \
    s_[4].u = b2[0]; s_[5].u = b2[1]; s_[6].u = b3[0]; s_[7].u = b3[1]; \
    s_[8].u = b4[0]; s_[9].u = b4[1];                             \
    _Pragma("unroll") for (int dx = 0; dx < 9; ++dx)              \
      _Pragma("unroll") for (int i = 0; i < 2; ++i)               \
        acc[18 + dx * 2 + i] = __builtin_amdgcn_fdot2(            \
            f_[i].h, s_[i + dx].h, acc[18 + dx * 2 + i], false);  \
  } while (0)

#pragma unroll 1
  for (int t = 0; t < 7; ++t) {             // cp 0..27
    ITER(0, 8, 1); ITER(1, 8, 1); ITER(2, 8, 1); ITER(3, 8, 1);
  }
  ITER(0, 8, 1);                            // cp=28, issues pair 31
  ITER(1, 8, 0);                            // cp=29 (12 out -> drain to 8)
  ITER(2, 4, 0);                            // cp=30
  ITER(3, 0, 0);                            // cp=31
#undef ITER
#undef PAIRI

  const float sc = 1.0f / 64.0f;
#pragma unroll
  for (int dx = 0; dx < 9; ++dx)
    *(float2*)(ob + (size_t)dx * PLANE) =
        make_float2(acc[dx * 2 + 0] * sc, acc[dx * 2 + 1] * sc);
  if (wv < 4) {                             // dy1 = dy0+1 <= 8: write it
#pragma unroll
    for (int dx = 0; dx < 9; ++dx)
      *(float2*)(ob + (size_t)(9 + dx) * PLANE) =
          make_float2(acc[18 + dx * 2 + 0] * sc, acc[18 + dx * 2 + 1] * sc);
  }
}

// ---- fallback (proven-correct fp32 path) if ws is too small ----
__global__ __launch_bounds__(576) void corr_fp32_fb(
    const float* __restrict__ first, const float* __restrict__ second,
    float* __restrict__ out)
{
  const int tid  = threadIdx.x;
  const int lane = tid & 63;
  const int wv   = tid >> 6;
  const int bid  = blockIdx.x;
  const int idx  = bid >> 3;
  const int h    = (bid & 7) * 16 + (idx & 15);
  const int b    = idx >> 4;
  const int l4   = lane * 4;
  const size_t plane = (size_t)HH * WW;
  float* obase = out + (((size_t)b * 81 + (size_t)wv * 9) * HH + h) * WW + l4;
  const int gh = h + wv - 4;
  if (gh < 0 || gh >= HH) {
    const float4 z = make_float4(0.f, 0.f, 0.f, 0.f);
#pragma unroll
    for (int dx = 0; dx < 9; ++dx) *(float4*)(obase + (size_t)dx * plane) = z;
    return;
  }
  const float* frow = first  + ((size_t)b * 64 * HH + h ) * WW;
  const float* srow = second + ((size_t)b * 64 * HH + gh) * WW;
  const bool zL = (lane == 0), zR = (lane == 63);
  const int offL = zL ? l4 : l4 - 4;
  const int offR = zR ? l4 : l4 + 4;
  float acc[9][4];
#pragma unroll
  for (int dx = 0; dx < 9; ++dx)
#pragma unroll
    for (int i = 0; i < 4; ++i) acc[dx][i] = 0.f;
#pragma unroll 2
  for (int c = 0; c < 64; ++c) {
    const size_t cp = (size_t)c * plane;
    float4 f  = *(const float4*)(frow + cp + l4);
    float4 aL = *(const float4*)(srow + cp + offL);
    float4 aM = *(const float4*)(srow + cp + l4);
    float4 aR = *(const float4*)(srow + cp + offR);
    if (zL) { aL.x = aL.y = aL.z = aL.w = 0.f; }
    if (zR) { aR.x = aR.y = aR.z = aR.w = 0.f; }
    const float fv[4]  = {f.x, f.y, f.z, f.w};
    const float sv[12] = {aL.x, aL.y, aL.z, aL.w, aM.x, aM.y, aM.z, aM.w,
                          aR.x, aR.y, aR.z, aR.w};
#pragma unroll
    for (int dx = 0; dx < 9; ++dx)
#pragma unroll
      for (int i = 0; i < 4; ++i)
        acc[dx][i] = fmaf(fv[i], sv[i + dx], acc[dx][i]);
  }
  const float sc = 1.0f / 64.0f;
#pragma unroll
  for (int dx = 0; dx < 9; ++dx) {
    float4 v = make_float4(acc[dx][0] * sc, acc[dx][1] * sc,
                           acc[dx][2] * sc, acc[dx][3] * sc);
    *(float4*)(obase + (size_t)dx * plane) = v;
  }
}

extern "C" void kernel_launch(void* const* d_in, const int* in_sizes, int n_in,
                              void* d_out, int out_size, void* d_ws, size_t ws_size,
                              hipStream_t stream) {
  const float* first  = (const float*)d_in[0];
  const float* second = (const float*)d_in[1];
  float* out = (float*)d_out;
  (void)in_sizes; (void)n_in; (void)out_size;

  if (ws_size >= (PACKED_DWORDS + 1024) * 4ull) {
    u32* psecond = (u32*)d_ws;
    u32* zws = psecond + ZOFF;
    pack_s  <<<dim3(4096), dim3(256), 0, stream>>>(second, psecond, zws);
    corr_f16<<<dim3(1024), dim3(320), 0, stream>>>(psecond, first, zws, out);
  } else {
    corr_fp32_fb<<<dim3(512), dim3(576), 0, stream>>>(first, second, out);
  }
}

// Round 17
// 52.887 us; speedup vs baseline: 5.9712x; 5.9712x over previous
//
#include <hip/hip_runtime.h>

#define HH 128
#define WW 256
#define DEPTH 4          // LDS/F ring slots per wave
#define AHEAD 3          // channel-pairs in flight; 3 vmem per pair
#define NCP 32           // 64 channels -> 32 channel-pairs
#define PLANE 32768      // H*W dwords per plane
#define PACKED_DWORDS 4194304ull   // packed S: 4 b * 32 cp * 32768

typedef unsigned int u32;
typedef _Float16 f16;
typedef f16 f16x2 __attribute__((ext_vector_type(2)));
typedef u32 u32x4 __attribute__((ext_vector_type(4)));

union U32H2 { u32 u; f16x2 h; };

// async global->LDS, 16B/lane: global src per-lane, LDS dest uniform base + lane*16.
__device__ __forceinline__ void gload_lds16(const u32* g, u32* l) {
  __builtin_amdgcn_global_load_lds(
      (const __attribute__((address_space(1))) u32*)g,
      (__attribute__((address_space(3))) u32*)l, 16, 0, 0);
}

__device__ __forceinline__ void waitv(int n) {   // n compile-time after unroll
  if      (n >= 6) asm volatile("s_waitcnt vmcnt(6)" ::: "memory");
  else if (n == 3) asm volatile("s_waitcnt vmcnt(3)" ::: "memory");
  else             asm volatile("s_waitcnt vmcnt(0)" ::: "memory");
}

// ---- pack S only: fp32 [b][c][h][w] -> dword=half2(c,c+1) at [b][c/2][h][w] ----
__global__ __launch_bounds__(256) void pack_s(
    const float* __restrict__ src, u32* __restrict__ dst)
{
  const int di  = blockIdx.x * 1024 + threadIdx.x * 4;
  const int p   = di & (PLANE - 1);
  const int cpb = di >> 15;
  const int bI  = cpb >> 5, cp = cpb & 31;
  const size_t s0 = ((size_t)(bI * 64 + cp * 2)) * PLANE + p;
  const float4 x = *(const float4*)(src + s0);
  const float4 y = *(const float4*)(src + s0 + PLANE);
  U32H2 h0, h1, h2, h3;
  h0.h = f16x2{(f16)x.x, (f16)y.x};
  h1.h = f16x2{(f16)x.y, (f16)y.y};
  h2.h = f16x2{(f16)x.z, (f16)y.z};
  h3.h = f16x2{(f16)x.w, (f16)y.w};
  *(u32x4*)(dst + di) = (u32x4){h0.u, h1.u, h2.u, h3.u};
}

// ---- correlation: block=(b,h,dy-triple), 3 waves (dy = 3*tri + wv).
// Inner loop byte-identical to the R13 champion; only decomposition changed.
// 1536 blocks -> 6 blocks/CU granularity; triples of one (b,h) share an XCD.
__global__ __launch_bounds__(192, 6) void corr_f16(
    const u32* __restrict__ ps, const float* __restrict__ first,
    float* __restrict__ out)
{
  __shared__ u32 lds[3][DEPTH * 264];              // 12672 B/block

  const int tid  = threadIdx.x;
  const int lane = tid & 63;
  const int wv   = __builtin_amdgcn_readfirstlane(tid >> 6);  // 0..2
  const int bid  = blockIdx.x;
  const int xcd  = bid & 7;                 // contiguous 16-row h band per XCD
  const int rest = bid >> 3;                // 0..191
  const int h    = xcd * 16 + (rest & 15);
  const int tmp  = rest >> 4;               // 0..11
  const int b    = tmp & 3;
  const int tri  = tmp >> 2;                // 0..2 -> same (b,h) triples same XCD
  const int dy   = tri * 3 + wv;            // 0..8
  const int l4   = lane * 4;

  float* obase = out + (((size_t)(b * 81 + dy * 9)) * HH + h) * WW + l4;
  const int gh = h + dy - 4;
  if (gh < 0 || gh >= HH) {                 // whole row OOB -> zeros, exit
    const float4 z = make_float4(0.f, 0.f, 0.f, 0.f);
#pragma unroll
    for (int dx = 0; dx < 9; ++dx) *(float4*)(obase + (size_t)dx * PLANE) = z;
    return;
  }

  u32* S = &lds[wv][0];                     // 4 slots x [4 pad | 256 | 4 pad]
  if (lane < DEPTH * 8) {                   // zero side-pads once (wave-private)
    const int slot = lane >> 3, pd = lane & 7;
    S[slot * 264 + (pd < 4 ? pd : 256 + pd)] = 0;
  }

  const u32*   sg = ps    + (size_t)(b * NCP) * PLANE + (size_t)gh * WW + l4;
  const float* fg = first + (size_t)(b * 64) * PLANE + (size_t)h * WW + l4;

  float4 frx[DEPTH], fry[DEPTH];            // F ring (fp32), compile-time indices

  auto pair = [&](int cp) {                 // 3 vmem: S-gload, F rows c and c+1
    const int slot = cp % DEPTH;
    gload_lds16(sg + (size_t)cp * PLANE, S + slot * 264 + 4);
    frx[slot] = *(const float4*)(fg + (size_t)(2 * cp) * PLANE);
    fry[slot] = *(const float4*)(fg + (size_t)(2 * cp + 1) * PLANE);
  };

#pragma unroll
  for (int cp = 0; cp < AHEAD; ++cp) pair(cp);    // 3 pairs = 9 vmem in flight

  float acc[36];
#pragma unroll
  for (int k = 0; k < 36; ++k) acc[k] = 0.f;

#pragma unroll
  for (int cp = 0; cp < NCP; ++cp) {
    const int rem = NCP - 1 - cp;
    // Drain pair cp (3 ops); leave at most AHEAD-1 pairs (=6 ops) in flight.
    waitv(3 * (rem < AHEAD - 1 ? rem : AHEAD - 1));
    __builtin_amdgcn_sched_barrier(0);      // rule 18: no ds_read above the wait
    const int slot = cp % DEPTH;
    const u32x4 s0 = *(const u32x4*)(S + slot * 264 + l4);       // w-4..w-1
    const u32x4 s1 = *(const u32x4*)(S + slot * 264 + l4 + 4);   // w..w+3
    const u32x4 s2 = *(const u32x4*)(S + slot * 264 + l4 + 8);   // w+4..w+7
    // RNE fp32->f16 pack of F (identical rounding to pack_s).
    U32H2 f_[4];
    f_[0].h = f16x2{(f16)frx[slot].x, (f16)fry[slot].x};
    f_[1].h = f16x2{(f16)frx[slot].y, (f16)fry[slot].y};
    f_[2].h = f16x2{(f16)frx[slot].z, (f16)fry[slot].z};
    f_[3].h = f16x2{(f16)frx[slot].w, (f16)fry[slot].w};
    if (cp + AHEAD < NCP) pair(cp + AHEAD); // landing regs freed by cvt above

    U32H2 s_[12];
#pragma unroll
    for (int j = 0; j < 4; ++j) { s_[j].u = s0[j]; s_[j + 4].u = s1[j]; s_[j + 8].u = s2[j]; }
#pragma unroll
    for (int dx = 0; dx < 9; ++dx)
#pragma unroll
      for (int i = 0; i < 4; ++i)
        acc[dx * 4 + i] = __builtin_amdgcn_fdot2(f_[i].h, s_[i + dx].h,
                                                 acc[dx * 4 + i], false);
  }

  const float sc = 1.0f / 64.0f;
#pragma unroll
  for (int dx = 0; dx < 9; ++dx) {
    float4 v = make_float4(acc[dx * 4 + 0] * sc, acc[dx * 4 + 1] * sc,
                           acc[dx * 4 + 2] * sc, acc[dx * 4 + 3] * sc);
    *(float4*)(obase + (size_t)dx * PLANE) = v;
  }
}

// ---- fallback (proven-correct fp32 path) if ws is too small ----
__global__ __launch_bounds__(576) void corr_fp32_fb(
    const float* __restrict__ first, const float* __restrict__ second,
    float* __restrict__ out)
{
  const int tid  = threadIdx.x;
  const int lane = tid & 63;
  const int wv   = tid >> 6;
  const int bid  = blockIdx.x;
  const int idx  = bid >> 3;
  const int h    = (bid & 7) * 16 + (idx & 15);
  const int b    = idx >> 4;
  const int l4   = lane * 4;
  const size_t plane = (size_t)HH * WW;
  float* obase = out + (((size_t)b * 81 + (size_t)wv * 9) * HH + h) * WW + l4;
  const int gh = h + wv - 4;
  if (gh < 0 || gh >= HH) {
    const float4 z = make_float4(0.f, 0.f, 0.f, 0.f);
#pragma unroll
    for (int dx = 0; dx < 9; ++dx) *(float4*)(obase + (size_t)dx * plane) = z;
    return;
  }
  const float* frow = first  + ((size_t)b * 64 * HH + h ) * WW;
  const float* srow = second + ((size_t)b * 64 * HH + gh) * WW;
  const bool zL = (lane == 0), zR = (lane == 63);
  const int offL = zL ? l4 : l4 - 4;
  const int offR = zR ? l4 : l4 + 4;
  float acc[9][4];
#pragma unroll
  for (int dx = 0; dx < 9; ++dx)
#pragma unroll
    for (int i = 0; i < 4; ++i) acc[dx][i] = 0.f;
#pragma unroll 2
  for (int c = 0; c < 64; ++c) {
    const size_t cp = (size_t)c * plane;
    float4 f  = *(const float4*)(frow + cp + l4);
    float4 aL = *(const float4*)(srow + cp + offL);
    float4 aM = *(const float4*)(srow + cp + l4);
    float4 aR = *(const float4*)(srow + cp + offR);
    if (zL) { aL.x = aL.y = aL.z = aL.w = 0.f; }
    if (zR) { aR.x = aR.y = aR.z = aR.w = 0.f; }
    const float fv[4]  = {f.x, f.y, f.z, f.w};
    const float sv[12] = {aL.x, aL.y, aL.z, aL.w, aM.x, aM.y, aM.z, aM.w,
                          aR.x, aR.y, aR.z, aR.w};
#pragma unroll
    for (int dx = 0; dx < 9; ++dx)
#pragma unroll
      for (int i = 0; i < 4; ++i)
        acc[dx][i] = fmaf(fv[i], sv[i + dx], acc[dx][i]);
  }
  const float sc = 1.0f / 64.0f;
#pragma unroll
  for (int dx = 0; dx < 9; ++dx) {
    float4 v = make_float4(acc[dx][0] * sc, acc[dx][1] * sc,
                           acc[dx][2] * sc, acc[dx][3] * sc);
    *(float4*)(obase + (size_t)dx * plane) = v;
  }
}

extern "C" void kernel_launch(void* const* d_in, const int* in_sizes, int n_in,
                              void* d_out, int out_size, void* d_ws, size_t ws_size,
                              hipStream_t stream) {
  const float* first  = (const float*)d_in[0];
  const float* second = (const float*)d_in[1];
  float* out = (float*)d_out;
  (void)in_sizes; (void)n_in; (void)out_size;

  if (ws_size >= PACKED_DWORDS * 4ull) {
    u32* psecond = (u32*)d_ws;
    pack_s  <<<dim3(4096), dim3(256), 0, stream>>>(second, psecond);
    corr_f16<<<dim3(1536), dim3(192), 0, stream>>>(psecond, first, out);
  } else {
    corr_fp32_fb<<<dim3(512), dim3(576), 0, stream>>>(first, second, out);
  }
}

// Round 18
// 37.913 us; speedup vs baseline: 8.3295x; 1.3950x over previous
//
#include <hip/hip_runtime.h>

#define HH 128
#define WW 256
#define DEPTH 4          // LDS/F ring slots per wave
#define AHEAD 3          // channel-pairs in flight; 3 vmem per pair
#define NCP 32           // 64 channels -> 32 channel-pairs
#define PLANE 32768      // H*W dwords per plane
#define PACKED_DWORDS 4194304ull   // packed S: 4 b * 32 cp * 32768

typedef unsigned int u32;
typedef _Float16 f16;
typedef f16 f16x2 __attribute__((ext_vector_type(2)));
typedef u32 u32x4 __attribute__((ext_vector_type(4)));

union U32H2 { u32 u; f16x2 h; };

// async global->LDS, 16B/lane: global src per-lane, LDS dest uniform base + lane*16.
__device__ __forceinline__ void gload_lds16(const u32* g, u32* l) {
  __builtin_amdgcn_global_load_lds(
      (const __attribute__((address_space(1))) u32*)g,
      (__attribute__((address_space(3))) u32*)l, 16, 0, 0);
}

// Stage A: drain only the S-gload (oldest op) of pair cp.
__device__ __forceinline__ void waitA(int rem) {   // compile-time after unroll
  if      (rem >= 2) asm volatile("s_waitcnt vmcnt(8)" ::: "memory");
  else if (rem == 1) asm volatile("s_waitcnt vmcnt(5)" ::: "memory");
  else               asm volatile("s_waitcnt vmcnt(2)" ::: "memory");
}
// Stage B: drain pair cp's two F loads (next-oldest), after pair(cp+3) issue.
__device__ __forceinline__ void waitB(int rem) {
  if      (rem >= 3) asm volatile("s_waitcnt vmcnt(9)" ::: "memory");
  else if (rem == 2) asm volatile("s_waitcnt vmcnt(6)" ::: "memory");
  else if (rem == 1) asm volatile("s_waitcnt vmcnt(3)" ::: "memory");
  else               asm volatile("s_waitcnt vmcnt(0)" ::: "memory");
}

// ---- pack S only: fp32 [b][c][h][w] -> dword=half2(c,c+1) at [b][c/2][h][w] ----
__global__ __launch_bounds__(256) void pack_s(
    const float* __restrict__ src, u32* __restrict__ dst)
{
  const int di  = blockIdx.x * 1024 + threadIdx.x * 4;
  const int p   = di & (PLANE - 1);
  const int cpb = di >> 15;
  const int bI  = cpb >> 5, cp = cpb & 31;
  const size_t s0 = ((size_t)(bI * 64 + cp * 2)) * PLANE + p;
  const float4 x = *(const float4*)(src + s0);
  const float4 y = *(const float4*)(src + s0 + PLANE);
  U32H2 h0, h1, h2, h3;
  h0.h = f16x2{(f16)x.x, (f16)y.x};
  h1.h = f16x2{(f16)x.y, (f16)y.y};
  h2.h = f16x2{(f16)x.z, (f16)y.z};
  h3.h = f16x2{(f16)x.w, (f16)y.w};
  *(u32x4*)(dst + di) = (u32x4){h0.u, h1.u, h2.u, h3.u};
}

// ---- correlation: block=(b,h), 9 dy-waves (R13 champion structure).
// Two-stage vmcnt: ds_reads overlap the F-load tail instead of waiting on it.
__global__ __launch_bounds__(576, 5) void corr_f16(
    const u32* __restrict__ ps, const float* __restrict__ first,
    float* __restrict__ out)
{
  __shared__ u32 lds[9][DEPTH * 264];              // 38016 B/block

  const int tid  = threadIdx.x;
  const int lane = tid & 63;
  const int dy   = __builtin_amdgcn_readfirstlane(tid >> 6);  // 0..8, wave-uniform
  const int bid  = blockIdx.x;
  const int xcd  = bid & 7;                 // contiguous 16-row h band per XCD
  const int idx  = bid >> 3;                // 0..63
  const int h    = xcd * 16 + (idx & 15);
  const int b    = idx >> 4;                // 0..3
  const int l4   = lane * 4;

  float* obase = out + (((size_t)(b * 81 + dy * 9)) * HH + h) * WW + l4;
  const int gh = h + dy - 4;
  if (gh < 0 || gh >= HH) {                 // whole row OOB -> zeros, exit
    const float4 z = make_float4(0.f, 0.f, 0.f, 0.f);
#pragma unroll
    for (int dx = 0; dx < 9; ++dx) *(float4*)(obase + (size_t)dx * PLANE) = z;
    return;
  }

  u32* S = &lds[dy][0];                     // 4 slots x [4 pad | 256 | 4 pad]
  if (lane < DEPTH * 8) {                   // zero side-pads once (wave-private)
    const int slot = lane >> 3, pd = lane & 7;
    S[slot * 264 + (pd < 4 ? pd : 256 + pd)] = 0;
  }

  const u32*   sg = ps    + (size_t)(b * NCP) * PLANE + (size_t)gh * WW + l4;
  const float* fg = first + (size_t)(b * 64) * PLANE + (size_t)h * WW + l4;

  float4 frx[DEPTH], fry[DEPTH];            // F ring (fp32), compile-time indices

  auto pair = [&](int cp) {                 // 3 vmem, order: S-gload, F c, F c+1
    const int slot = cp % DEPTH;
    gload_lds16(sg + (size_t)cp * PLANE, S + slot * 264 + 4);
    frx[slot] = *(const float4*)(fg + (size_t)(2 * cp) * PLANE);
    fry[slot] = *(const float4*)(fg + (size_t)(2 * cp + 1) * PLANE);
  };

#pragma unroll
  for (int cp = 0; cp < AHEAD; ++cp) pair(cp);    // 3 pairs = 9 vmem in flight

  float acc[36];
#pragma unroll
  for (int k = 0; k < 36; ++k) acc[k] = 0.f;

#pragma unroll
  for (int cp = 0; cp < NCP; ++cp) {
    const int rem = NCP - 1 - cp;
    waitA(rem);                             // S-gload of cp landed in LDS
    __builtin_amdgcn_sched_barrier(0);      // rule 18: no ds_read above the wait
    const int slot = cp % DEPTH;
    const u32x4 s0 = *(const u32x4*)(S + slot * 264 + l4);       // w-4..w-1
    const u32x4 s1 = *(const u32x4*)(S + slot * 264 + l4 + 4);   // w..w+3
    const u32x4 s2 = *(const u32x4*)(S + slot * 264 + l4 + 8);   // w+4..w+7
    if (cp + AHEAD < NCP) pair(cp + AHEAD); // slot (cp-1)%4 was consumed at cp-1

    waitB(rem);                             // F of cp in regs; later pairs fly on
    __builtin_amdgcn_sched_barrier(0);
    U32H2 f_[4];                            // RNE fp32->f16 pack (matches pack_s)
    f_[0].h = f16x2{(f16)frx[slot].x, (f16)fry[slot].x};
    f_[1].h = f16x2{(f16)frx[slot].y, (f16)fry[slot].y};
    f_[2].h = f16x2{(f16)frx[slot].z, (f16)fry[slot].z};
    f_[3].h = f16x2{(f16)frx[slot].w, (f16)fry[slot].w};

    U32H2 s_[12];
#pragma unroll
    for (int j = 0; j < 4; ++j) { s_[j].u = s0[j]; s_[j + 4].u = s1[j]; s_[j + 8].u = s2[j]; }
#pragma unroll
    for (int dx = 0; dx < 9; ++dx)
#pragma unroll
      for (int i = 0; i < 4; ++i)
        acc[dx * 4 + i] = __builtin_amdgcn_fdot2(f_[i].h, s_[i + dx].h,
                                                 acc[dx * 4 + i], false);
  }

  const float sc = 1.0f / 64.0f;
#pragma unroll
  for (int dx = 0; dx < 9; ++dx) {
    float4 v = make_float4(acc[dx * 4 + 0] * sc, acc[dx * 4 + 1] * sc,
                           acc[dx * 4 + 2] * sc, acc[dx * 4 + 3] * sc);
    *(float4*)(obase + (size_t)dx * PLANE) = v;
  }
}

// ---- fallback (proven-correct fp32 path) if ws is too small ----
__global__ __launch_bounds__(576) void corr_fp32_fb(
    const float* __restrict__ first, const float* __restrict__ second,
    float* __restrict__ out)
{
  const int tid  = threadIdx.x;
  const int lane = tid & 63;
  const int wv   = tid >> 6;
  const int bid  = blockIdx.x;
  const int idx  = bid >> 3;
  const int h    = (bid & 7) * 16 + (idx & 15);
  const int b    = idx >> 4;
  const int l4   = lane * 4;
  const size_t plane = (size_t)HH * WW;
  float* obase = out + (((size_t)b * 81 + (size_t)wv * 9) * HH + h) * WW + l4;
  const int gh = h + wv - 4;
  if (gh < 0 || gh >= HH) {
    const float4 z = make_float4(0.f, 0.f, 0.f, 0.f);
#pragma unroll
    for (int dx = 0; dx < 9; ++dx) *(float4*)(obase + (size_t)dx * plane) = z;
    return;
  }
  const float* frow = first  + ((size_t)b * 64 * HH + h ) * WW;
  const float* srow = second + ((size_t)b * 64 * HH + gh) * WW;
  const bool zL = (lane == 0), zR = (lane == 63);
  const int offL = zL ? l4 : l4 - 4;
  const int offR = zR ? l4 : l4 + 4;
  float acc[9][4];
#pragma unroll
  for (int dx = 0; dx < 9; ++dx)
#pragma unroll
    for (int i = 0; i < 4; ++i) acc[dx][i] = 0.f;
#pragma unroll 2
  for (int c = 0; c < 64; ++c) {
    const size_t cp = (size_t)c * plane;
    float4 f  = *(const float4*)(frow + cp + l4);
    float4 aL = *(const float4*)(srow + cp + offL);
    float4 aM = *(const float4*)(srow + cp + l4);
    float4 aR = *(const float4*)(srow + cp + offR);
    if (zL) { aL.x = aL.y = aL.z = aL.w = 0.f; }
    if (zR) { aR.x = aR.y = aR.z = aR.w = 0.f; }
    const float fv[4]  = {f.x, f.y, f.z, f.w};
    const float sv[12] = {aL.x, aL.y, aL.z, aL.w, aM.x, aM.y, aM.z, aM.w,
                          aR.x, aR.y, aR.z, aR.w};
#pragma unroll
    for (int dx = 0; dx < 9; ++dx)
#pragma unroll
      for (int i = 0; i < 4; ++i)
        acc[dx][i] = fmaf(fv[i], sv[i + dx], acc[dx][i]);
  }
  const float sc = 1.0f / 64.0f;
#pragma unroll
  for (int dx = 0; dx < 9; ++dx) {
    float4 v = make_float4(acc[dx][0] * sc, acc[dx][1] * sc,
                           acc[dx][2] * sc, acc[dx][3] * sc);
    *(float4*)(obase + (size_t)dx * plane) = v;
  }
}

extern "C" void kernel_launch(void* const* d_in, const int* in_sizes, int n_in,
                              void* d_out, int out_size, void* d_ws, size_t ws_size,
                              hipStream_t stream) {
  const float* first  = (const float*)d_in[0];
  const float* second = (const float*)d_in[1];
  float* out = (float*)d_out;
  (void)in_sizes; (void)n_in; (void)out_size;

  if (ws_size >= PACKED_DWORDS * 4ull) {
    u32* psecond = (u32*)d_ws;
    pack_s  <<<dim3(4096), dim3(256), 0, stream>>>(second, psecond);
    corr_f16<<<dim3(512),  dim3(576), 0, stream>>>(psecond, first, out);
  } else {
    corr_fp32_fb<<<dim3(512), dim3(576), 0, stream>>>(first, second, out);
  }
}